// Round 21
// baseline (195.916 us; speedup 1.0000x reference)
//
#include <hip/hip_runtime.h>
#include <hip/hip_bf16.h>
#include <cstdint>
#include <cstddef>

#define NN 64
#define CC 192
#define VV 25
#define TTT 300
#define TC 8            // t per block, 1 per wave (8 waves, 512 threads)
#define NTC 38          // ceil(300/8); last chunk: seg0 real (296-299), seg1 pad
#define GRID (NN*NTC)   // 2432 (% 8 == 0)

// workspace (u16 element offsets)
#define MFRAG_OFF 40960 // M fragment-major: 72 frags x 64 lanes x 8 bf16
#define WML_OFF 77824   // wm linear bf16[192]

// LDS map (bytes) — 45,536 total -> 2 blocks/CU at 16 waves (VGPR<=128):
//  [0, 14336)      raw f32 DMA buffers, 2 x 7,168 (400 chunks*16B + pad)
//  [14336, 20960)  bf16 transpose tile, 2 x 3,312 (207 rows x 16B)
//  [20960, 45536)  8 x 3KB wave scratch (Y-bounce / SIM)
#define RAW_STRIDE 7168
#define TILE_OFF 14336
#define TILE_STRIDE 3312
#define YS_OFF 20960
#define LDS_TOTAL 45536

typedef unsigned short u16;
typedef unsigned long long u64;
typedef short bf16x8 __attribute__((ext_vector_type(8)));
typedef float f32x4 __attribute__((ext_vector_type(4)));
typedef float f4 __attribute__((ext_vector_type(4)));

__device__ __forceinline__ u16 f2bf(float x) {
  union { float f; uint32_t u; } v; v.f = x;
  uint32_t r = v.u + 0x7fffu + ((v.u >> 16) & 1u);
  return (u16)(r >> 16);
}
__device__ __forceinline__ u64 pack4(f32x4 a) {
  return (u64)f2bf(a[0]) | ((u64)f2bf(a[1]) << 16) |
         ((u64)f2bf(a[2]) << 32) | ((u64)f2bf(a[3]) << 48);
}

// prep: blocks 0..191 -> M fragment-major; block 192 -> wm linear bf16.
__global__ __launch_bounds__(192) void prep(const float* __restrict__ w1,
                                            const float* __restrict__ w2,
                                            const float* __restrict__ wm,
                                            u16* __restrict__ mb) {
  int c2 = threadIdx.x, b = blockIdx.x;
  if (b < CC) {
    float s = 0.f;
    for (int d = 0; d < CC; ++d) s += w1[d * CC + b] * w2[d * CC + c2];
    u16 h = f2bf(s);
    int cc = b >> 5, half = (b >> 4) & 1, lr = b & 15;
    int ks = c2 >> 5, l8 = (c2 & 31) >> 3, e = c2 & 7;
    int lane = l8 * 16 + lr;
    mb[MFRAG_OFF + (((cc * 2 + half) * 6 + ks) * 64 + lane) * 8 + e] = h;
  } else {
    mb[WML_OFF + c2] = f2bf(wm[c2]);
  }
}

// fused: block = (n, 8 t), 512 threads, wave = 1 t. R18's proven DMA schedule
// at half block size: 24 rounds x 400 chunks (chunk k = cl*50 + v*2 + seg,
// 16B each), counted vmcnt(1) keeps next round's DMA in flight across the
// barriers. 45.5KB LDS -> 2 blocks/CU: block A's compute tail (M via L1,
// MFMA) overlaps block B's staging (LDS pipe + barriers). M stays in GLOBAL
// (fragment-major; identical addresses across waves -> L1 broadcast).
__global__ __launch_bounds__(512, 4) void fused(const float* __restrict__ x1,
                                                const u16* __restrict__ mb,
                                                float* __restrict__ out) {
  __shared__ char lds[LDS_TOTAL];
  const int tid = threadIdx.x;
  const int wid = tid >> 6, lane = tid & 63, lr = lane & 15, lq = lane >> 4;
  char* YS = lds + YS_OFF + wid * 3072;

  // XCD-chunked bijective swizzle (GRID % 8 == 0). Paired blocks (ch, ch+1)
  // share x1 64B lines and land on the SAME XCD (b and b+8 -> same b&7).
  int b = blockIdx.x;
  int logical = (b & 7) * (GRID / 8) + (b >> 3);
  int n = logical / NTC;
  int ch = logical - n * NTC;
  int t0 = ch * TC;
  int t = t0 + wid;
  const bool lastch = (t0 + TC > TTT);

  const float* xb = x1 + (size_t)n * (CC * VV * TTT) + t0;

  // DMA issue for round ct: waves 0..6 each one global_load_lds (64 chunks).
  auto issueDMA = [&](int ct) {
    if (wid < 7) {
      int k = wid * 64 + lane;
      int kk = k > 399 ? 399 : k;              // clamp; extras land in pad
      int cl = kk / 50;
      int rem = kk - cl * 50;
      int v = rem >> 1;
      int seg = kk & 1;
      int sege = (lastch && seg == 1) ? 0 : seg;  // last chunk: seg1 dup
      const float* src = xb + (size_t)(ct * 8 + cl) * (VV * TTT) + v * TTT + sege * 4;
      char* dst = lds + (ct & 1) * RAW_STRIDE + wid * 1024;
      __builtin_amdgcn_global_load_lds(
          (const __attribute__((address_space(1))) void*)src,
          (__attribute__((address_space(3))) void*)dst, 16, 0, 0);
    }
  };

  asm volatile("s_waitcnt vmcnt(0)" ::: "memory");
  issueDMA(0);

  // ---- staging pipeline: 24 rounds (R18 schedule, counted vmcnt) ----
  bf16x8 sf[2][6];
  for (int ct = 0; ct < 24; ++ct) {
    __builtin_amdgcn_s_barrier();              // A: transpose(ct-1) done
    if (ct < 23) {
      issueDMA(ct + 1);
      asm volatile("s_waitcnt vmcnt(1)" ::: "memory");  // own DMA(ct) landed
    } else {
      asm volatile("s_waitcnt vmcnt(0)" ::: "memory");
    }
    __builtin_amdgcn_s_barrier();              // B: everyone's DMA(ct) landed

    // transpose: raw[ct&1] f32 -> tile[ct&1] bf16 (row (seg*4+dt)*25+v, col cl)
    if (tid < 400) {
      int cl = tid / 50;
      int rem = tid - cl * 50;
      int v = rem >> 1;
      int seg = tid & 1;
      f4 a = *(const f4*)(lds + (ct & 1) * RAW_STRIDE + tid * 16);
      char* tb = lds + TILE_OFF + (ct & 1) * TILE_STRIDE + (size_t)v * 16 + cl * 2;
      *(u16*)(tb + (size_t)(seg * 4 + 0) * 400) = f2bf(a[0]);
      *(u16*)(tb + (size_t)(seg * 4 + 1) * 400) = f2bf(a[1]);
      *(u16*)(tb + (size_t)(seg * 4 + 2) * 400) = f2bf(a[2]);
      *(u16*)(tb + (size_t)(seg * 4 + 3) * 400) = f2bf(a[3]);
    }

    // harvest(ct-1) from tile[(ct-1)&1] (complete pre-A this iter)
    if (ct > 0) {
      const int cp = ct - 1;
      if (lq == (cp & 3)) {
        const char* tp = lds + TILE_OFF + (cp & 1) * TILE_STRIDE;
        sf[0][cp >> 2] = *(const bf16x8*)(tp + (size_t)(wid * VV + lr) * 16);
        sf[1][cp >> 2] = *(const bf16x8*)(tp + (size_t)(wid * VV + 16 + lr) * 16);
      }
    }
  }
  __syncthreads();                             // transpose(23) visible
  {
    const int cp = 23;
    if (lq == (cp & 3)) {
      const char* tp = lds + TILE_OFF + (cp & 1) * TILE_STRIDE;
      sf[0][cp >> 2] = *(const bf16x8*)(tp + (size_t)(wid * VV + lr) * 16);
      sf[1][cp >> 2] = *(const bf16x8*)(tp + (size_t)(wid * VV + 16 + lr) * 16);
    }
  }

  // ---- register compute tail (wave-private; M from global/L1) ----
  f32x4 pacc[2][2], macc[2];
  #pragma unroll
  for (int i = 0; i < 2; ++i) {
    macc[i] = (f32x4){0.f, 0.f, 0.f, 0.f};
    #pragma unroll
    for (int jx = 0; jx < 2; ++jx) pacc[i][jx] = (f32x4){0.f, 0.f, 0.f, 0.f};
  }
  const u16* mf = mb + MFRAG_OFF;

  #pragma unroll
  for (int cc = 0; cc < 6; ++cc) {
    f32x4 y00 = (f32x4){0.f,0.f,0.f,0.f}, y01 = y00, y10 = y00, y11 = y00;
    #pragma unroll
    for (int ks = 0; ks < 6; ++ks) {
      bf16x8 a0 = *(const bf16x8*)(mf + ((cc * 12 + ks) * 64 + lane) * 8);
      bf16x8 a1 = *(const bf16x8*)(mf + ((cc * 12 + 6 + ks) * 64 + lane) * 8);
      y00 = __builtin_amdgcn_mfma_f32_16x16x32_bf16(a0, sf[0][ks], y00, 0, 0, 0);
      y01 = __builtin_amdgcn_mfma_f32_16x16x32_bf16(a1, sf[0][ks], y01, 0, 0, 0);
      y10 = __builtin_amdgcn_mfma_f32_16x16x32_bf16(a0, sf[1][ks], y10, 0, 0, 0);
      y11 = __builtin_amdgcn_mfma_f32_16x16x32_bf16(a1, sf[1][ks], y11, 0, 0, 0);
    }
    *(u64*)(YS + (lr) * 80 + lq * 8) = pack4(y00);
    *(u64*)(YS + (lr) * 80 + 32 + lq * 8) = pack4(y01);
    *(u64*)(YS + (16 + lr) * 80 + lq * 8) = pack4(y10);
    *(u64*)(YS + (16 + lr) * 80 + 32 + lq * 8) = pack4(y11);

    bf16x8 wmf = *(const bf16x8*)(mb + WML_OFF + cc * 32 + lq * 8);
    macc[0] = __builtin_amdgcn_mfma_f32_16x16x32_bf16(sf[0][cc], wmf, macc[0], 0, 0, 0);
    macc[1] = __builtin_amdgcn_mfma_f32_16x16x32_bf16(sf[1][cc], wmf, macc[1], 0, 0, 0);

    bf16x8 B0 = *(const bf16x8*)(YS + (lr) * 80 + lq * 16);
    bf16x8 B1 = *(const bf16x8*)(YS + (16 + lr) * 80 + lq * 16);
    pacc[0][0] = __builtin_amdgcn_mfma_f32_16x16x32_bf16(sf[0][cc], B0, pacc[0][0], 0, 0, 0);
    pacc[0][1] = __builtin_amdgcn_mfma_f32_16x16x32_bf16(sf[0][cc], B1, pacc[0][1], 0, 0, 0);
    pacc[1][0] = __builtin_amdgcn_mfma_f32_16x16x32_bf16(sf[1][cc], B0, pacc[1][0], 0, 0, 0);
    pacc[1][1] = __builtin_amdgcn_mfma_f32_16x16x32_bf16(sf[1][cc], B1, pacc[1][1], 0, 0, 0);
  }

  // ---- wave-private epilogue (Y-bounce dead; reuse as SIM [27][28] f32) ----
  float* SIMW = (float*)YS;
  #pragma unroll
  for (int vt = 0; vt < 2; ++vt)
    #pragma unroll
    for (int wt = 0; wt < 2; ++wt) {
      int w = wt * 16 + lr;
      if (w < VV) {
        #pragma unroll
        for (int i = 0; i < 4; ++i) {
          int v = vt * 16 + lq * 4 + i;
          if (v < VV) SIMW[v * 28 + w] = pacc[vt][wt][i];
        }
      }
    }
  if (lr == 0) {
    #pragma unroll
    for (int j = 0; j < 2; ++j)
      #pragma unroll
      for (int i = 0; i < 4; ++i) {
        int v = j * 16 + lq * 4 + i;
        if (v < VV) SIMW[26 * 28 + v] = macc[j][i];
      }
  }

  f32x4 r[6];
  float r24 = 0.f, rs = 0.f, cs = 0.f;
  if (lane < VV) {
    const f32x4* rp = (const f32x4*)(SIMW + lane * 28);
    #pragma unroll
    for (int k = 0; k < 6; ++k) r[k] = rp[k];
    r24 = SIMW[lane * 28 + 24];
    f32x4 s4 = r[0] + r[1] + r[2] + r[3] + r[4] + r[5];
    rs = s4[0] + s4[1] + s4[2] + s4[3] + r24;
    #pragma unroll
    for (int v = 0; v < VV; ++v) cs += SIMW[v * 28 + lane];
    SIMW[25 * 28 + lane] = cs;
  }
  float x = (lane < VV) ? cs : 0.f;
  #pragma unroll
  for (int s = 1; s < 64; s <<= 1) x += __shfl_xor(x, s);
  const float tot = x;

  if (lane < VV) {
    const int v = lane;
    const float base = -rs * 0.04f + tot * 0.0016f;
    const float isc = 0.07216878364870323f;  // 1/sqrt(192)
    const f32x4* cp4 = (const f32x4*)(SIMW + 25 * 28);
    const f32x4* mp = (const f32x4*)(SIMW + 26 * 28);
    float l[VV];
    float mx = -1e30f;
    #pragma unroll
    for (int k = 0; k < 6; ++k) {
      f32x4 val = (r[k] - cp4[k] * 0.04f + base) * isc + mp[k];
      #pragma unroll
      for (int j = 0; j < 4; ++j) {
        l[k * 4 + j] = val[j];
        mx = fmaxf(mx, val[j]);
      }
    }
    {
      float val = (r24 - SIMW[25 * 28 + 24] * 0.04f + base) * isc + SIMW[26 * 28 + 24];
      l[24] = val;
      mx = fmaxf(mx, val);
    }
    float sum = 0.f;
    #pragma unroll
    for (int w = 0; w < VV; ++w) { float e = __expf(l[w] - mx); l[w] = e; sum += e; }
    float rsc = 1.0f / sum;
    f32x4* wp = (f32x4*)(SIMW + v * 28);
    #pragma unroll
    for (int k = 0; k < 6; ++k) {
      f32x4 o = (f32x4){l[k*4] * rsc, l[k*4+1] * rsc, l[k*4+2] * rsc, l[k*4+3] * rsc};
      wp[k] = o;
    }
    SIMW[v * 28 + 24] = l[24] * rsc;
  }

  if (t < TTT) {
    float* ob = out + (size_t)(n * TTT + t) * 625;
    int v = (lane * 1311) >> 15;
    int w = lane - v * 25;
    #pragma unroll
    for (int i = 0; i < 10; ++i) {
      int idx = lane + i * 64;
      if (idx < 625) ob[idx] = SIMW[v * 28 + w];
      w += 14; v += 2;
      if (w >= 25) { w -= 25; ++v; }
    }
  }
}

extern "C" void kernel_launch(void* const* d_in, const int* in_sizes, int n_in,
                              void* d_out, int out_size, void* d_ws, size_t ws_size,
                              hipStream_t stream) {
  const float* x1 = (const float*)d_in[0];
  const float* w1 = (const float*)d_in[1];
  const float* w2 = (const float*)d_in[2];
  const float* wm = (const float*)d_in[3];
  float* out = (float*)d_out;
  u16* mb = (u16*)d_ws;  // ~156 KB used

  hipLaunchKernelGGL(prep, dim3(CC + 1), dim3(CC), 0, stream, w1, w2, wm, mb);
  hipLaunchKernelGGL(fused, dim3(GRID), dim3(512), 0, stream, x1, mb, out);
}

// Round 22
// 163.601 us; speedup vs baseline: 1.1975x; 1.1975x over previous
//
#include <hip/hip_runtime.h>
#include <hip/hip_bf16.h>
#include <cstdint>
#include <cstddef>

#define NN 64
#define CC 192
#define VV 25
#define TTT 300
#define TC 16           // t per block, 1 per wave (16 waves)
#define NTC 19          // ceil(300/16); last chunk: segs 0..2 real, seg 3 pad
#define GRID (NN*NTC)   // 1216 (% 8 == 0)

// workspace (u16 element offsets). M frags + wm contiguous: one 74,112B copy.
#define MFRAG_OFF 40960
#define WML_OFF 77824

// LDS map (bytes):
//  [0, 26624)        raw f32 DMA buffers, 2 x 13,312
//  [26624, 39648)    bf16 transpose tile, 2 x 6,512 (407 rows x 16B)
//  [39648, 88800)    16 x 3KB wave scratch (Y-bounce / SIM)
//  [88800, 162528)   M fragments (73,728B)
//  [162528, 162912)  wm bf16[192]
#define RAW_STRIDE 13312
#define TILE_OFF 26624
#define TILE_STRIDE 6512
#define YS_OFF 39648
#define MLDS_OFF 88800
#define WMLDS_OFF 162528
#define LDS_TOTAL 162912
#define MCPY_CHUNKS 4632   // 74,112B / 16

typedef unsigned short u16;
typedef unsigned long long u64;
typedef short bf16x8 __attribute__((ext_vector_type(8)));
typedef float f32x4 __attribute__((ext_vector_type(4)));
typedef float f4 __attribute__((ext_vector_type(4)));
typedef int i32x4 __attribute__((ext_vector_type(4)));

__device__ __forceinline__ u16 f2bf(float x) {
  union { float f; uint32_t u; } v; v.f = x;
  uint32_t r = v.u + 0x7fffu + ((v.u >> 16) & 1u);
  return (u16)(r >> 16);
}
__device__ __forceinline__ u64 pack4(f32x4 a) {
  return (u64)f2bf(a[0]) | ((u64)f2bf(a[1]) << 16) |
         ((u64)f2bf(a[2]) << 32) | ((u64)f2bf(a[3]) << 48);
}

// prep: blocks 0..191 -> M fragment-major; block 192 -> wm linear bf16.
__global__ __launch_bounds__(192) void prep(const float* __restrict__ w1,
                                            const float* __restrict__ w2,
                                            const float* __restrict__ wm,
                                            u16* __restrict__ mb) {
  int c2 = threadIdx.x, b = blockIdx.x;
  if (b < CC) {
    float s = 0.f;
    for (int d = 0; d < CC; ++d) s += w1[d * CC + b] * w2[d * CC + c2];
    u16 h = f2bf(s);
    int cc = b >> 5, half = (b >> 4) & 1, lr = b & 15;
    int ks = c2 >> 5, l8 = (c2 & 31) >> 3, e = c2 & 7;
    int lane = l8 * 16 + lr;
    mb[MFRAG_OFF + (((cc * 2 + half) * 6 + ks) * 64 + lane) * 8 + e] = h;
  } else {
    mb[WML_OFF + c2] = f2bf(wm[c2]);
  }
}

// Issue one round's global loads — not used (DMA path); kept out. (no-op)

// fused: block = (n, 16 t), 1024 threads, wave = 1 t.
// Staging: 24 rounds of c-tile 8 via global_load_lds DMA (no VGPR round-trip):
//   chunk k=(cl*25+v)*4+seg (16B, 4 consecutive chunks = one 64B line, t0 is
//   64B-aligned). Per round each wave issues ONE DMA (64 chunks); next round's
//   DMA is issued BEFORE `s_waitcnt vmcnt(1)` + raw s_barrier, so loads stay
//   in flight across barriers (MLP independent of VGPR budget).
//   Pipeline per iter: [A barrier] issue(ct+1) -> vmcnt(1) -> [B barrier] ->
//   transpose(ct) raw->tile[ct&1] -> harvest(ct-1) from tile[(ct-1)&1].
// Compute/epilogue: M+wm in LDS, Y-bounce, stats centering, softmax.
__global__ __launch_bounds__(1024, 4) void fused(const float* __restrict__ x1,
                                                 const u16* __restrict__ mb,
                                                 float* __restrict__ out) {
  extern __shared__ char lds[];
  const int tid = threadIdx.x;
  const int wid = tid >> 6, lane = tid & 63, lr = lane & 15, lq = lane >> 4;
  char* YS = lds + YS_OFF + wid * 3072;

  // ---- cooperative M+wm -> LDS copy ----
  {
    const char* src = (const char*)mb + (size_t)MFRAG_OFF * 2;
    #pragma unroll
    for (int k = 0; k < 5; ++k) {
      int i = k * 1024 + tid;
      if (i < MCPY_CHUNKS)
        *(i32x4*)(lds + MLDS_OFF + i * 16) = *(const i32x4*)(src + i * 16);
    }
  }

  // XCD-chunked bijective swizzle (GRID % 8 == 0)
  int b = blockIdx.x;
  int logical = (b & 7) * (GRID / 8) + (b >> 3);
  int n = logical / NTC;
  int ch = logical - n * NTC;
  int t0 = ch * TC;
  int t = t0 + wid;
  const bool lastch = (t0 + TC > TTT);

  const float* xb = x1 + (size_t)n * (CC * VV * TTT) + t0;

  // DMA issue for round ct: waves 0..12 each one global_load_lds (64 chunks).
  auto issue = [&](int ct) {
    if (wid < 13) {
      int k = wid * 64 + lane;
      int kk = k > 799 ? 799 : k;              // clamp; extras land in pad
      int cl = kk / 100;
      int rem = kk - cl * 100;
      int v = rem >> 2;
      int seg = kk & 3;
      int sege = (lastch && seg == 3) ? 2 : seg;  // last chunk: seg3 dup (garbage rows)
      const float* src = xb + (size_t)(ct * 8 + cl) * (VV * TTT) + v * TTT + sege * 4;
      char* dst = lds + (ct & 1) * RAW_STRIDE + wid * 1024;
      __builtin_amdgcn_global_load_lds(
          (const __attribute__((address_space(1))) void*)src,
          (__attribute__((address_space(3))) void*)dst, 16, 0, 0);
    }
  };

  bf16x8 sf[2][6];
  asm volatile("s_waitcnt vmcnt(0)" ::: "memory");
  issue(0);
  for (int ct = 0; ct < 24; ++ct) {
    __builtin_amdgcn_s_barrier();              // A: transpose(ct-1) done everywhere
    if (ct < 23) {
      issue(ct + 1);
      asm volatile("s_waitcnt vmcnt(1)" ::: "memory");  // own DMA(ct) landed
    } else {
      asm volatile("s_waitcnt vmcnt(0)" ::: "memory");
    }
    __builtin_amdgcn_s_barrier();              // B: everyone's DMA(ct) landed

    // transpose: raw[ct&1] f32 -> tile[ct&1] bf16 (rows (seg*4+dt)*25+v, col cl)
    if (tid < 800) {
      int cl = tid / 100;
      int rem = tid - cl * 100;
      int v = rem >> 2;
      int seg = tid & 3;
      f4 a = *(const f4*)(lds + (ct & 1) * RAW_STRIDE + tid * 16);
      char* tb = lds + TILE_OFF + (ct & 1) * TILE_STRIDE + (size_t)v * 16 + cl * 2;
      *(u16*)(tb + (size_t)(seg * 4 + 0) * 25 * 16) = f2bf(a[0]);
      *(u16*)(tb + (size_t)(seg * 4 + 1) * 25 * 16) = f2bf(a[1]);
      *(u16*)(tb + (size_t)(seg * 4 + 2) * 25 * 16) = f2bf(a[2]);
      *(u16*)(tb + (size_t)(seg * 4 + 3) * 25 * 16) = f2bf(a[3]);
    }

    // harvest(ct-1): tile[(ct-1)&1] complete for all waves (pre-A this iter).
    if (ct > 0) {
      int cp = ct - 1;                          // c range [cp*8, cp*8+8)
      if (lq == (cp & 3)) {
        const char* tp = lds + TILE_OFF + (cp & 1) * TILE_STRIDE;
        bf16x8 f0 = *(const bf16x8*)(tp + (size_t)(wid * VV + lr) * 16);
        bf16x8 f1 = *(const bf16x8*)(tp + (size_t)(wid * VV + 16 + lr) * 16);
        sf[0][cp >> 2] = f0;
        sf[1][cp >> 2] = f1;
      }
    }
  }
  __syncthreads();                              // transpose(23) visible
  {
    int cp = 23;
    if (lq == (cp & 3)) {
      const char* tp = lds + TILE_OFF + (cp & 1) * TILE_STRIDE;
      sf[0][cp >> 2] = *(const bf16x8*)(tp + (size_t)(wid * VV + lr) * 16);
      sf[1][cp >> 2] = *(const bf16x8*)(tp + (size_t)(wid * VV + 16 + lr) * 16);
    }
  }

  // ---- register compute (no barriers; A-frags + wm from LDS) ----
  f32x4 pacc[2][2], macc[2];
  #pragma unroll
  for (int i = 0; i < 2; ++i) {
    macc[i] = (f32x4){0.f, 0.f, 0.f, 0.f};
    #pragma unroll
    for (int jx = 0; jx < 2; ++jx) pacc[i][jx] = (f32x4){0.f, 0.f, 0.f, 0.f};
  }

  const char* mfl = lds + MLDS_OFF;
  #pragma unroll
  for (int cc = 0; cc < 6; ++cc) {
    f32x4 y00 = (f32x4){0.f,0.f,0.f,0.f}, y01 = y00, y10 = y00, y11 = y00;
    #pragma unroll
    for (int ks = 0; ks < 6; ++ks) {
      bf16x8 a0 = *(const bf16x8*)(mfl + (size_t)((cc * 12 + ks) * 64 + lane) * 16);
      bf16x8 a1 = *(const bf16x8*)(mfl + (size_t)((cc * 12 + 6 + ks) * 64 + lane) * 16);
      y00 = __builtin_amdgcn_mfma_f32_16x16x32_bf16(a0, sf[0][ks], y00, 0, 0, 0);
      y01 = __builtin_amdgcn_mfma_f32_16x16x32_bf16(a1, sf[0][ks], y01, 0, 0, 0);
      y10 = __builtin_amdgcn_mfma_f32_16x16x32_bf16(a0, sf[1][ks], y10, 0, 0, 0);
      y11 = __builtin_amdgcn_mfma_f32_16x16x32_bf16(a1, sf[1][ks], y11, 0, 0, 0);
    }
    *(u64*)(YS + (lr) * 80 + lq * 8) = pack4(y00);
    *(u64*)(YS + (lr) * 80 + 32 + lq * 8) = pack4(y01);
    *(u64*)(YS + (16 + lr) * 80 + lq * 8) = pack4(y10);
    *(u64*)(YS + (16 + lr) * 80 + 32 + lq * 8) = pack4(y11);

    bf16x8 wmf = *(const bf16x8*)(lds + WMLDS_OFF + (cc * 32 + lq * 8) * 2);
    macc[0] = __builtin_amdgcn_mfma_f32_16x16x32_bf16(sf[0][cc], wmf, macc[0], 0, 0, 0);
    macc[1] = __builtin_amdgcn_mfma_f32_16x16x32_bf16(sf[1][cc], wmf, macc[1], 0, 0, 0);

    bf16x8 B0 = *(const bf16x8*)(YS + (lr) * 80 + lq * 16);
    bf16x8 B1 = *(const bf16x8*)(YS + (16 + lr) * 80 + lq * 16);
    pacc[0][0] = __builtin_amdgcn_mfma_f32_16x16x32_bf16(sf[0][cc], B0, pacc[0][0], 0, 0, 0);
    pacc[0][1] = __builtin_amdgcn_mfma_f32_16x16x32_bf16(sf[0][cc], B1, pacc[0][1], 0, 0, 0);
    pacc[1][0] = __builtin_amdgcn_mfma_f32_16x16x32_bf16(sf[1][cc], B0, pacc[1][0], 0, 0, 0);
    pacc[1][1] = __builtin_amdgcn_mfma_f32_16x16x32_bf16(sf[1][cc], B1, pacc[1][1], 0, 0, 0);
  }

  // ---- wave-private epilogue (Y-bounce dead; reuse as SIM [27][28] f32) ----
  float* SIMW = (float*)YS;
  #pragma unroll
  for (int vt = 0; vt < 2; ++vt)
    #pragma unroll
    for (int wt = 0; wt < 2; ++wt) {
      int w = wt * 16 + lr;
      if (w < VV) {
        #pragma unroll
        for (int i = 0; i < 4; ++i) {
          int v = vt * 16 + lq * 4 + i;
          if (v < VV) SIMW[v * 28 + w] = pacc[vt][wt][i];
        }
      }
    }
  if (lr == 0) {
    #pragma unroll
    for (int j = 0; j < 2; ++j)
      #pragma unroll
      for (int i = 0; i < 4; ++i) {
        int v = j * 16 + lq * 4 + i;
        if (v < VV) SIMW[26 * 28 + v] = macc[j][i];
      }
  }

  f32x4 r[6];
  float r24 = 0.f, rs = 0.f, cs = 0.f;
  if (lane < VV) {
    const f32x4* rp = (const f32x4*)(SIMW + lane * 28);
    #pragma unroll
    for (int k = 0; k < 6; ++k) r[k] = rp[k];
    r24 = SIMW[lane * 28 + 24];
    f32x4 s4 = r[0] + r[1] + r[2] + r[3] + r[4] + r[5];
    rs = s4[0] + s4[1] + s4[2] + s4[3] + r24;
    #pragma unroll
    for (int v = 0; v < VV; ++v) cs += SIMW[v * 28 + lane];
    SIMW[25 * 28 + lane] = cs;
  }
  float x = (lane < VV) ? cs : 0.f;
  #pragma unroll
  for (int s = 1; s < 64; s <<= 1) x += __shfl_xor(x, s);
  const float tot = x;

  if (lane < VV) {
    const int v = lane;
    const float base = -rs * 0.04f + tot * 0.0016f;
    const float isc = 0.07216878364870323f;  // 1/sqrt(192)
    const f32x4* cp4 = (const f32x4*)(SIMW + 25 * 28);
    const f32x4* mp = (const f32x4*)(SIMW + 26 * 28);
    float l[VV];
    float mx = -1e30f;
    #pragma unroll
    for (int k = 0; k < 6; ++k) {
      f32x4 val = (r[k] - cp4[k] * 0.04f + base) * isc + mp[k];
      #pragma unroll
      for (int j = 0; j < 4; ++j) {
        l[k * 4 + j] = val[j];
        mx = fmaxf(mx, val[j]);
      }
    }
    {
      float val = (r24 - SIMW[25 * 28 + 24] * 0.04f + base) * isc + SIMW[26 * 28 + 24];
      l[24] = val;
      mx = fmaxf(mx, val);
    }
    float sum = 0.f;
    #pragma unroll
    for (int w = 0; w < VV; ++w) { float e = __expf(l[w] - mx); l[w] = e; sum += e; }
    float rsc = 1.0f / sum;
    f32x4* wp = (f32x4*)(SIMW + v * 28);
    #pragma unroll
    for (int k = 0; k < 6; ++k) {
      f32x4 o = (f32x4){l[k*4] * rsc, l[k*4+1] * rsc, l[k*4+2] * rsc, l[k*4+3] * rsc};
      wp[k] = o;
    }
    SIMW[v * 28 + 24] = l[24] * rsc;
  }

  if (t < TTT) {
    float* ob = out + (size_t)(n * TTT + t) * 625;
    int v = (lane * 1311) >> 15;
    int w = lane - v * 25;
    #pragma unroll
    for (int i = 0; i < 10; ++i) {
      int idx = lane + i * 64;
      if (idx < 625) ob[idx] = SIMW[v * 28 + w];
      w += 14; v += 2;
      if (w >= 25) { w -= 25; ++v; }
    }
  }
}

extern "C" void kernel_launch(void* const* d_in, const int* in_sizes, int n_in,
                              void* d_out, int out_size, void* d_ws, size_t ws_size,
                              hipStream_t stream) {
  const float* x1 = (const float*)d_in[0];
  const float* w1 = (const float*)d_in[1];
  const float* w2 = (const float*)d_in[2];
  const float* wm = (const float*)d_in[3];
  float* out = (float*)d_out;
  u16* mb = (u16*)d_ws;  // ~156 KB used

  hipLaunchKernelGGL(prep, dim3(CC + 1), dim3(CC), 0, stream, w1, w2, wm, mb);
  hipLaunchKernelGGL(fused, dim3(GRID), dim3(1024), LDS_TOTAL, stream, x1, mb, out);
}

// Round 24
// 160.525 us; speedup vs baseline: 1.2205x; 1.0192x over previous
//
#include <hip/hip_runtime.h>
#include <hip/hip_bf16.h>
#include <cstdint>
#include <cstddef>

#define NN 64
#define CC 192
#define VV 25
#define TTT 300
#define TC 16           // t per block, 1 per wave (16 waves)
#define NTC 19          // ceil(300/16); last chunk: segs 0..2 real, seg 3 pad
#define GRID (NN*NTC)   // 1216 (% 8 == 0)

// workspace (u16 element offsets). M frags + wm contiguous: one 74,112B copy.
#define MFRAG_OFF 40960
#define WML_OFF 77824

// LDS map (bytes), total 140,384:
//  [0, 53248)        raw f32 DMA ring, 4 x 13,312 (ct&3)
//  [53248, 66272)    bf16 transpose tile, 2 x 6,512 (407 rows x 16B)
//  [66272, 140000)   M fragments (73,728B)
//  [140000, 140384)  wm bf16[192]
//  YS (16 x 3KB wave scratch) ALIASES [0, 49152) — raw ring is dead after the
//  final staging sync.
#define RAW_STRIDE 13312
#define TILE_OFF 53248
#define TILE_STRIDE 6512
#define MLDS_OFF 66272
#define WMLDS_OFF 140000
#define LDS_TOTAL 140384
#define MCPY_CHUNKS 4632   // 74,112B / 16

typedef unsigned short u16;
typedef unsigned long long u64;
typedef short bf16x8 __attribute__((ext_vector_type(8)));
typedef float f32x4 __attribute__((ext_vector_type(4)));
typedef float f4 __attribute__((ext_vector_type(4)));
typedef int i32x4 __attribute__((ext_vector_type(4)));

__device__ __forceinline__ u16 f2bf(float x) {
  union { float f; uint32_t u; } v; v.f = x;
  uint32_t r = v.u + 0x7fffu + ((v.u >> 16) & 1u);
  return (u16)(r >> 16);
}
__device__ __forceinline__ u64 pack4(f32x4 a) {
  return (u64)f2bf(a[0]) | ((u64)f2bf(a[1]) << 16) |
         ((u64)f2bf(a[2]) << 32) | ((u64)f2bf(a[3]) << 48);
}

// prep: blocks 0..191 -> M fragment-major; block 192 -> wm linear bf16.
__global__ __launch_bounds__(192) void prep(const float* __restrict__ w1,
                                            const float* __restrict__ w2,
                                            const float* __restrict__ wm,
                                            u16* __restrict__ mb) {
  int c2 = threadIdx.x, b = blockIdx.x;
  if (b < CC) {
    float s = 0.f;
    for (int d = 0; d < CC; ++d) s += w1[d * CC + b] * w2[d * CC + c2];
    u16 h = f2bf(s);
    int cc = b >> 5, half = (b >> 4) & 1, lr = b & 15;
    int ks = c2 >> 5, l8 = (c2 & 31) >> 3, e = c2 & 7;
    int lane = l8 * 16 + lr;
    mb[MFRAG_OFF + (((cc * 2 + half) * 6 + ks) * 64 + lane) * 8 + e] = h;
  } else {
    mb[WML_OFF + c2] = f2bf(wm[c2]);
  }
}

// fused: block = (n, 16 t), 1024 threads, wave = 1 t.
// Staging: 24 rounds, 4-deep raw ring, ONE barrier per round:
//   { s_waitcnt vmcnt(<=2) lgkmcnt(0)  [own DMA(ct) landed AND own ds_writes
//     of transpose(ct-1) drained — raw s_barrier does NOT drain LDS ops, this
//     was R23's intermittent race]; s_barrier; issue(ct+3); transpose(ct);
//     harvest(ct-1) }.
// DMA(ct) has 3 round-times in flight. Compute/epilogue: R18 verbatim.
__global__ __launch_bounds__(1024, 4) void fused(const float* __restrict__ x1,
                                                 const u16* __restrict__ mb,
                                                 float* __restrict__ out) {
  extern __shared__ char lds[];
  const int tid = threadIdx.x;
  const int wid = tid >> 6, lane = tid & 63, lr = lane & 15, lq = lane >> 4;
  char* YS = lds + wid * 3072;  // aliases raw ring; valid after final sync

  // ---- cooperative M+wm -> LDS copy ----
  {
    const char* src = (const char*)mb + (size_t)MFRAG_OFF * 2;
    #pragma unroll
    for (int k = 0; k < 5; ++k) {
      int i = k * 1024 + tid;
      if (i < MCPY_CHUNKS)
        *(i32x4*)(lds + MLDS_OFF + i * 16) = *(const i32x4*)(src + i * 16);
    }
  }

  // XCD-chunked bijective swizzle (GRID % 8 == 0)
  int b = blockIdx.x;
  int logical = (b & 7) * (GRID / 8) + (b >> 3);
  int n = logical / NTC;
  int ch = logical - n * NTC;
  int t0 = ch * TC;
  int t = t0 + wid;
  const bool lastch = (t0 + TC > TTT);

  const float* xb = x1 + (size_t)n * (CC * VV * TTT) + t0;

  // DMA issue for round ct: waves 0..12 each one global_load_lds (64 chunks).
  auto issue = [&](int ct) {
    if (wid < 13) {
      int k = wid * 64 + lane;
      int kk = k > 799 ? 799 : k;              // clamp; extras land in pad
      int cl = kk / 100;
      int rem = kk - cl * 100;
      int v = rem >> 2;
      int seg = kk & 3;
      int sege = (lastch && seg == 3) ? 2 : seg;  // last chunk: seg3 dup
      const float* src = xb + (size_t)(ct * 8 + cl) * (VV * TTT) + v * TTT + sege * 4;
      char* dst = lds + (ct & 3) * RAW_STRIDE + wid * 1024;
      __builtin_amdgcn_global_load_lds(
          (const __attribute__((address_space(1))) void*)src,
          (__attribute__((address_space(3))) void*)dst, 16, 0, 0);
    }
  };

  bf16x8 sf[2][6];
  asm volatile("s_waitcnt vmcnt(0)" ::: "memory");
  issue(0);
  issue(1);
  issue(2);

  for (int ct = 0; ct < 24; ++ct) {
    // Drain: own DMA(ct) landed (vmcnt) AND own prior ds_writes visible (lgkm)
    if (ct < 22)       asm volatile("s_waitcnt vmcnt(2) lgkmcnt(0)" ::: "memory");
    else if (ct == 22) asm volatile("s_waitcnt vmcnt(1) lgkmcnt(0)" ::: "memory");
    else               asm volatile("s_waitcnt vmcnt(0) lgkmcnt(0)" ::: "memory");
    __builtin_amdgcn_s_barrier();  // all DMA(ct) landed; all transpose(ct-1) done

    if (ct < 21) issue(ct + 3);    // overwrites raw[(ct-1)&3] -- safe post-barrier

    // transpose: raw[ct&3] f32 -> tile[ct&1] bf16 (rows (seg*4+dt)*25+v, col cl)
    if (tid < 800) {
      int cl = tid / 100;
      int rem = tid - cl * 100;
      int v = rem >> 2;
      int seg = tid & 3;
      f4 a = *(const f4*)(lds + (ct & 3) * RAW_STRIDE + tid * 16);
      char* tb = lds + TILE_OFF + (ct & 1) * TILE_STRIDE + (size_t)v * 16 + cl * 2;
      *(u16*)(tb + (size_t)(seg * 4 + 0) * 25 * 16) = f2bf(a[0]);
      *(u16*)(tb + (size_t)(seg * 4 + 1) * 25 * 16) = f2bf(a[1]);
      *(u16*)(tb + (size_t)(seg * 4 + 2) * 25 * 16) = f2bf(a[2]);
      *(u16*)(tb + (size_t)(seg * 4 + 3) * 25 * 16) = f2bf(a[3]);
    }

    // harvest(ct-1): tile[(ct-1)&1] complete for all waves (pre-barrier)
    if (ct > 0) {
      int cp = ct - 1;                          // c range [cp*8, cp*8+8)
      if (lq == (cp & 3)) {
        const char* tp = lds + TILE_OFF + (cp & 1) * TILE_STRIDE;
        sf[0][cp >> 2] = *(const bf16x8*)(tp + (size_t)(wid * VV + lr) * 16);
        sf[1][cp >> 2] = *(const bf16x8*)(tp + (size_t)(wid * VV + 16 + lr) * 16);
      }
    }
  }
  __syncthreads();                              // full drain; transpose(23) visible
  {
    int cp = 23;
    if (lq == (cp & 3)) {
      const char* tp = lds + TILE_OFF + (cp & 1) * TILE_STRIDE;
      sf[0][cp >> 2] = *(const bf16x8*)(tp + (size_t)(wid * VV + lr) * 16);
      sf[1][cp >> 2] = *(const bf16x8*)(tp + (size_t)(wid * VV + 16 + lr) * 16);
    }
  }

  // ---- register compute (no barriers; A-frags + wm from LDS) ----
  f32x4 pacc[2][2], macc[2];
  #pragma unroll
  for (int i = 0; i < 2; ++i) {
    macc[i] = (f32x4){0.f, 0.f, 0.f, 0.f};
    #pragma unroll
    for (int jx = 0; jx < 2; ++jx) pacc[i][jx] = (f32x4){0.f, 0.f, 0.f, 0.f};
  }

  const char* mfl = lds + MLDS_OFF;
  #pragma unroll
  for (int cc = 0; cc < 6; ++cc) {
    f32x4 y00 = (f32x4){0.f,0.f,0.f,0.f}, y01 = y00, y10 = y00, y11 = y00;
    #pragma unroll
    for (int ks = 0; ks < 6; ++ks) {
      bf16x8 a0 = *(const bf16x8*)(mfl + (size_t)((cc * 12 + ks) * 64 + lane) * 16);
      bf16x8 a1 = *(const bf16x8*)(mfl + (size_t)((cc * 12 + 6 + ks) * 64 + lane) * 16);
      y00 = __builtin_amdgcn_mfma_f32_16x16x32_bf16(a0, sf[0][ks], y00, 0, 0, 0);
      y01 = __builtin_amdgcn_mfma_f32_16x16x32_bf16(a1, sf[0][ks], y01, 0, 0, 0);
      y10 = __builtin_amdgcn_mfma_f32_16x16x32_bf16(a0, sf[1][ks], y10, 0, 0, 0);
      y11 = __builtin_amdgcn_mfma_f32_16x16x32_bf16(a1, sf[1][ks], y11, 0, 0, 0);
    }
    *(u64*)(YS + (lr) * 80 + lq * 8) = pack4(y00);
    *(u64*)(YS + (lr) * 80 + 32 + lq * 8) = pack4(y01);
    *(u64*)(YS + (16 + lr) * 80 + lq * 8) = pack4(y10);
    *(u64*)(YS + (16 + lr) * 80 + 32 + lq * 8) = pack4(y11);

    bf16x8 wmf = *(const bf16x8*)(lds + WMLDS_OFF + (cc * 32 + lq * 8) * 2);
    macc[0] = __builtin_amdgcn_mfma_f32_16x16x32_bf16(sf[0][cc], wmf, macc[0], 0, 0, 0);
    macc[1] = __builtin_amdgcn_mfma_f32_16x16x32_bf16(sf[1][cc], wmf, macc[1], 0, 0, 0);

    bf16x8 B0 = *(const bf16x8*)(YS + (lr) * 80 + lq * 16);
    bf16x8 B1 = *(const bf16x8*)(YS + (16 + lr) * 80 + lq * 16);
    pacc[0][0] = __builtin_amdgcn_mfma_f32_16x16x32_bf16(sf[0][cc], B0, pacc[0][0], 0, 0, 0);
    pacc[0][1] = __builtin_amdgcn_mfma_f32_16x16x32_bf16(sf[0][cc], B1, pacc[0][1], 0, 0, 0);
    pacc[1][0] = __builtin_amdgcn_mfma_f32_16x16x32_bf16(sf[1][cc], B0, pacc[1][0], 0, 0, 0);
    pacc[1][1] = __builtin_amdgcn_mfma_f32_16x16x32_bf16(sf[1][cc], B1, pacc[1][1], 0, 0, 0);
  }

  // ---- wave-private epilogue (Y-bounce dead; reuse as SIM [27][28] f32) ----
  float* SIMW = (float*)YS;
  #pragma unroll
  for (int vt = 0; vt < 2; ++vt)
    #pragma unroll
    for (int wt = 0; wt < 2; ++wt) {
      int w = wt * 16 + lr;
      if (w < VV) {
        #pragma unroll
        for (int i = 0; i < 4; ++i) {
          int v = vt * 16 + lq * 4 + i;
          if (v < VV) SIMW[v * 28 + w] = pacc[vt][wt][i];
        }
      }
    }
  if (lr == 0) {
    #pragma unroll
    for (int j = 0; j < 2; ++j)
      #pragma unroll
      for (int i = 0; i < 4; ++i) {
        int v = j * 16 + lq * 4 + i;
        if (v < VV) SIMW[26 * 28 + v] = macc[j][i];
      }
  }

  f32x4 r[6];
  float r24 = 0.f, rs = 0.f, cs = 0.f;
  if (lane < VV) {
    const f32x4* rp = (const f32x4*)(SIMW + lane * 28);
    #pragma unroll
    for (int k = 0; k < 6; ++k) r[k] = rp[k];
    r24 = SIMW[lane * 28 + 24];
    f32x4 s4 = r[0] + r[1] + r[2] + r[3] + r[4] + r[5];
    rs = s4[0] + s4[1] + s4[2] + s4[3] + r24;
    #pragma unroll
    for (int v = 0; v < VV; ++v) cs += SIMW[v * 28 + lane];
    SIMW[25 * 28 + lane] = cs;
  }
  float x = (lane < VV) ? cs : 0.f;
  #pragma unroll
  for (int s = 1; s < 64; s <<= 1) x += __shfl_xor(x, s);
  const float tot = x;

  if (lane < VV) {
    const int v = lane;
    const float base = -rs * 0.04f + tot * 0.0016f;
    const float isc = 0.07216878364870323f;  // 1/sqrt(192)
    const f32x4* cp4 = (const f32x4*)(SIMW + 25 * 28);
    const f32x4* mp = (const f32x4*)(SIMW + 26 * 28);
    float l[VV];
    float mx = -1e30f;
    #pragma unroll
    for (int k = 0; k < 6; ++k) {
      f32x4 val = (r[k] - cp4[k] * 0.04f + base) * isc + mp[k];
      #pragma unroll
      for (int j = 0; j < 4; ++j) {
        l[k * 4 + j] = val[j];
        mx = fmaxf(mx, val[j]);
      }
    }
    {
      float val = (r24 - SIMW[25 * 28 + 24] * 0.04f + base) * isc + SIMW[26 * 28 + 24];
      l[24] = val;
      mx = fmaxf(mx, val);
    }
    float sum = 0.f;
    #pragma unroll
    for (int w = 0; w < VV; ++w) { float e = __expf(l[w] - mx); l[w] = e; sum += e; }
    float rsc = 1.0f / sum;
    f32x4* wp = (f32x4*)(SIMW + v * 28);
    #pragma unroll
    for (int k = 0; k < 6; ++k) {
      f32x4 o = (f32x4){l[k*4] * rsc, l[k*4+1] * rsc, l[k*4+2] * rsc, l[k*4+3] * rsc};
      wp[k] = o;
    }
    SIMW[v * 28 + 24] = l[24] * rsc;
  }

  if (t < TTT) {
    float* ob = out + (size_t)(n * TTT + t) * 625;
    int v = (lane * 1311) >> 15;
    int w = lane - v * 25;
    #pragma unroll
    for (int i = 0; i < 10; ++i) {
      int idx = lane + i * 64;
      if (idx < 625) ob[idx] = SIMW[v * 28 + w];
      w += 14; v += 2;
      if (w >= 25) { w -= 25; ++v; }
    }
  }
}

extern "C" void kernel_launch(void* const* d_in, const int* in_sizes, int n_in,
                              void* d_out, int out_size, void* d_ws, size_t ws_size,
                              hipStream_t stream) {
  const float* x1 = (const float*)d_in[0];
  const float* w1 = (const float*)d_in[1];
  const float* w2 = (const float*)d_in[2];
  const float* wm = (const float*)d_in[3];
  float* out = (float*)d_out;
  u16* mb = (u16*)d_ws;  // ~156 KB used

  hipLaunchKernelGGL(prep, dim3(CC + 1), dim3(CC), 0, stream, w1, w2, wm, mb);
  hipLaunchKernelGGL(fused, dim3(GRID), dim3(1024), LDS_TOTAL, stream, x1, mb, out);
}